// Round 2
// baseline (9739.335 us; speedup 1.0000x reference)
//
#include <hip/hip_runtime.h>
#include <cmath>

#define BS_TOK 32768      // B*S
#define DMODEL 512
#define NHEAD 8
#define DHEAD 64
#define NLAYER 3
#define FFDIM 2048
#define NCLS 6
#define BATCH 32
#define SEQ 1024
#define QKVW 1536         // 3*D

// ---------------- embedding + sinusoidal PE ----------------
__global__ __launch_bounds__(128) void embed_pe_kernel(const int* __restrict__ tokens,
                                                       const float* __restrict__ emb,
                                                       float* __restrict__ X) {
    int t = blockIdx.x;            // token index 0..32767
    int pos = t & (SEQ - 1);
    int tok = tokens[t];
    int d0 = threadIdx.x * 4;      // 128 threads * 4 = 512
    float4 e = *(const float4*)(emb + (size_t)tok * DMODEL + d0);
    const float c = -9.210340371976184f / 512.0f;   // -ln(10000)/D
    float div0 = expf((float)d0 * c);
    float div1 = expf((float)(d0 + 2) * c);
    float a0 = (float)pos * div0;
    float a1 = (float)pos * div1;
    e.x += sinf(a0); e.y += cosf(a0);
    e.z += sinf(a1); e.w += cosf(a1);
    *(float4*)(X + (size_t)t * DMODEL + d0) = e;
}

// ---------------- fp32 tiled GEMM: C = A[M,K] @ B[K,N] + bias ----------------
// 128x128 block tile, BK=8, 256 threads, 8x8 per thread. (used for QKV proj)
__global__ __launch_bounds__(256) void gemm_f32_kernel(const float* __restrict__ A,
                                                       const float* __restrict__ Bm,
                                                       const float* __restrict__ bias,
                                                       float* __restrict__ Cm,
                                                       int M, int N, int K) {
    __shared__ float As[8][128];   // [k][m]
    __shared__ float Bs[8][128];   // [k][n]
    int bm = blockIdx.y * 128;
    int bn = blockIdx.x * 128;
    int tid = threadIdx.x;
    int ar = tid >> 1, ac = (tid & 1) * 4;     // A tile: 128 rows x 8 k
    int br = tid >> 5, bc = (tid & 31) * 4;    // B tile: 8 rows x 128 n
    int tr = tid >> 4, tc = tid & 15;

    float acc[8][8];
#pragma unroll
    for (int i = 0; i < 8; i++)
#pragma unroll
        for (int j = 0; j < 8; j++) acc[i][j] = 0.f;

    for (int k0 = 0; k0 < K; k0 += 8) {
        float4 av = *(const float4*)(A + (size_t)(bm + ar) * K + k0 + ac);
        float4 bv = *(const float4*)(Bm + (size_t)(k0 + br) * N + bn + bc);
        As[ac + 0][ar] = av.x;
        As[ac + 1][ar] = av.y;
        As[ac + 2][ar] = av.z;
        As[ac + 3][ar] = av.w;
        *(float4*)&Bs[br][bc] = bv;
        __syncthreads();
#pragma unroll
        for (int kk = 0; kk < 8; kk++) {
            float4 a0 = *(float4*)&As[kk][tr * 8];
            float4 a1 = *(float4*)&As[kk][tr * 8 + 4];
            float4 b0 = *(float4*)&Bs[kk][tc * 8];
            float4 b1 = *(float4*)&Bs[kk][tc * 8 + 4];
            float a[8] = {a0.x, a0.y, a0.z, a0.w, a1.x, a1.y, a1.z, a1.w};
            float b[8] = {b0.x, b0.y, b0.z, b0.w, b1.x, b1.y, b1.z, b1.w};
#pragma unroll
            for (int i = 0; i < 8; i++)
#pragma unroll
                for (int j = 0; j < 8; j++) acc[i][j] += a[i] * b[j];
        }
        __syncthreads();
    }

    float bvals[8];
    {
        float4 t0 = *(const float4*)(bias + bn + tc * 8);
        float4 t1 = *(const float4*)(bias + bn + tc * 8 + 4);
        bvals[0] = t0.x; bvals[1] = t0.y; bvals[2] = t0.z; bvals[3] = t0.w;
        bvals[4] = t1.x; bvals[5] = t1.y; bvals[6] = t1.z; bvals[7] = t1.w;
    }
#pragma unroll
    for (int i = 0; i < 8; i++) {
        size_t row = (size_t)(bm + tr * 8 + i);
        *(float4*)(Cm + row * N + bn + tc * 8) =
            make_float4(acc[i][0] + bvals[0], acc[i][1] + bvals[1],
                        acc[i][2] + bvals[2], acc[i][3] + bvals[3]);
        *(float4*)(Cm + row * N + bn + tc * 8 + 4) =
            make_float4(acc[i][4] + bvals[4], acc[i][5] + bvals[5],
                        acc[i][6] + bvals[6], acc[i][7] + bvals[7]);
    }
}

// ---------------- fused out-proj + bias + residual + LayerNorm ----------------
// C[32,512] tile = A[32,512] @ W[512,512]; then per-row LN; writes X in place.
// 256 threads: tr=tid>>6 (0..3) -> 8 rows each; tc=tid&63 -> 8 cols each.
// One wave (64 lanes) owns 8 complete rows -> wave-shuffle LN reduction.
__global__ __launch_bounds__(256) void proj_ln_kernel(const float* __restrict__ A,
                                                      const float* __restrict__ W,
                                                      const float* __restrict__ bias,
                                                      const float* __restrict__ gamma,
                                                      const float* __restrict__ beta,
                                                      float* __restrict__ Xc) {
    __shared__ float As[8][32];    // [k][m]
    __shared__ float Bs[8][512];   // [k][n]
    int bm = blockIdx.x * 32;
    int tid = threadIdx.x;
    int tr = tid >> 6, tc = tid & 63;

    float acc[8][8];
#pragma unroll
    for (int i = 0; i < 8; i++)
#pragma unroll
        for (int j = 0; j < 8; j++) acc[i][j] = 0.f;

    for (int k0 = 0; k0 < DMODEL; k0 += 8) {
        if (tid < 64) {            // A tile: 32 rows x 8 k = 64 float4
            int r = tid >> 1, kc = (tid & 1) * 4;
            float4 av = *(const float4*)(A + (size_t)(bm + r) * DMODEL + k0 + kc);
            As[kc + 0][r] = av.x;
            As[kc + 1][r] = av.y;
            As[kc + 2][r] = av.z;
            As[kc + 3][r] = av.w;
        }
        {                          // B tile: 8 rows x 512 = 1024 float4, 4 per thread
            int brow = tid >> 5, bcol = (tid & 31) * 16;
#pragma unroll
            for (int u = 0; u < 4; u++)
                *(float4*)&Bs[brow][bcol + u * 4] =
                    *(const float4*)(W + (size_t)(k0 + brow) * DMODEL + bcol + u * 4);
        }
        __syncthreads();
#pragma unroll
        for (int kk = 0; kk < 8; kk++) {
            float4 b0 = *(float4*)&Bs[kk][tc * 8];
            float4 b1 = *(float4*)&Bs[kk][tc * 8 + 4];
            float b[8] = {b0.x, b0.y, b0.z, b0.w, b1.x, b1.y, b1.z, b1.w};
#pragma unroll
            for (int i = 0; i < 8; i++) {
                float a = As[kk][tr * 8 + i];
#pragma unroll
                for (int j = 0; j < 8; j++) acc[i][j] += a * b[j];
            }
        }
        __syncthreads();
    }

    float g[8], bt[8], bv[8];
    {
        float4 t0 = *(const float4*)(gamma + tc * 8);
        float4 t1 = *(const float4*)(gamma + tc * 8 + 4);
        g[0]=t0.x; g[1]=t0.y; g[2]=t0.z; g[3]=t0.w; g[4]=t1.x; g[5]=t1.y; g[6]=t1.z; g[7]=t1.w;
        t0 = *(const float4*)(beta + tc * 8);
        t1 = *(const float4*)(beta + tc * 8 + 4);
        bt[0]=t0.x; bt[1]=t0.y; bt[2]=t0.z; bt[3]=t0.w; bt[4]=t1.x; bt[5]=t1.y; bt[6]=t1.z; bt[7]=t1.w;
        t0 = *(const float4*)(bias + tc * 8);
        t1 = *(const float4*)(bias + tc * 8 + 4);
        bv[0]=t0.x; bv[1]=t0.y; bv[2]=t0.z; bv[3]=t0.w; bv[4]=t1.x; bv[5]=t1.y; bv[6]=t1.z; bv[7]=t1.w;
    }

#pragma unroll
    for (int i = 0; i < 8; i++) {
        size_t row = (size_t)(bm + tr * 8 + i);
        float o[8];
        float4 r0 = *(const float4*)(Xc + row * DMODEL + tc * 8);
        float4 r1 = *(const float4*)(Xc + row * DMODEL + tc * 8 + 4);
        o[0] = acc[i][0] + bv[0] + r0.x; o[1] = acc[i][1] + bv[1] + r0.y;
        o[2] = acc[i][2] + bv[2] + r0.z; o[3] = acc[i][3] + bv[3] + r0.w;
        o[4] = acc[i][4] + bv[4] + r1.x; o[5] = acc[i][5] + bv[5] + r1.y;
        o[6] = acc[i][6] + bv[6] + r1.z; o[7] = acc[i][7] + bv[7] + r1.w;
        float s = 0.f, sq = 0.f;
#pragma unroll
        for (int j = 0; j < 8; j++) { s += o[j]; sq += o[j] * o[j]; }
#pragma unroll
        for (int mask = 1; mask < 64; mask <<= 1) {
            s += __shfl_xor(s, mask);
            sq += __shfl_xor(sq, mask);
        }
        float mean = s * (1.f / 512.f);
        float var = sq * (1.f / 512.f) - mean * mean;
        float rstd = rsqrtf(var + 1e-5f);
        *(float4*)(Xc + row * DMODEL + tc * 8) =
            make_float4((o[0]-mean)*rstd*g[0]+bt[0], (o[1]-mean)*rstd*g[1]+bt[1],
                        (o[2]-mean)*rstd*g[2]+bt[2], (o[3]-mean)*rstd*g[3]+bt[3]);
        *(float4*)(Xc + row * DMODEL + tc * 8 + 4) =
            make_float4((o[4]-mean)*rstd*g[4]+bt[4], (o[5]-mean)*rstd*g[5]+bt[5],
                        (o[6]-mean)*rstd*g[6]+bt[6], (o[7]-mean)*rstd*g[7]+bt[7]);
    }
}

// ---------------- flash attention (fp32), Q-tile 64, full (non-causal) ----------------
// qkv layout per token row (1536): head h -> [h*192 .. ]: q(64), k(64), v(64)
// qkv/O pointers are chunk-local; blockIdx.y = local_b*8 + h.
__global__ __launch_bounds__(256) void attn_kernel(const float* __restrict__ qkv,
                                                   float* __restrict__ O) {
    __shared__ float Qs[64][68];   // Q rows (pre-scaled by 1/8)
    __shared__ float KPs[64][68];  // K^T (Kt[d][c]) during S; P[r][c] during PV
    __shared__ float Vs[64][68];   // V[k][d]
    int bh = blockIdx.y;
    int b = bh >> 3, h = bh & 7;
    int q0 = blockIdx.x * 64;
    int tid = threadIdx.x;
    int ty = tid >> 4, tx = tid & 15;
    int lr = tid >> 2, lp = (tid & 3) * 16;   // loader: row, d-chunk

    {   // load Q tile, scaled
        const float* qb = qkv + (size_t)(b * SEQ + q0 + lr) * QKVW + h * 192;
#pragma unroll
        for (int u = 0; u < 4; u++) {
            float4 v = *(const float4*)(qb + lp + u * 4);
            *(float4*)&Qs[lr][lp + u * 4] =
                make_float4(v.x * 0.125f, v.y * 0.125f, v.z * 0.125f, v.w * 0.125f);
        }
    }

    float m_prev[4], lsum[4], acc[4][4];
#pragma unroll
    for (int i = 0; i < 4; i++) {
        m_prev[i] = -1e30f; lsum[i] = 0.f;
#pragma unroll
        for (int j = 0; j < 4; j++) acc[i][j] = 0.f;
    }

    for (int jt = 0; jt < SEQ / 64; jt++) {
        __syncthreads();   // protect KPs/Vs from previous-iter readers (covers Q load 1st iter)
        {
            const float* kb = qkv + (size_t)(b * SEQ + jt * 64 + lr) * QKVW + h * 192 + 64;
            const float* vb = kb + 64;
#pragma unroll
            for (int u = 0; u < 4; u++) {
                float4 kv = *(const float4*)(kb + lp + u * 4);
                KPs[lp + u * 4 + 0][lr] = kv.x;
                KPs[lp + u * 4 + 1][lr] = kv.y;
                KPs[lp + u * 4 + 2][lr] = kv.z;
                KPs[lp + u * 4 + 3][lr] = kv.w;
                *(float4*)&Vs[lr][lp + u * 4] = *(const float4*)(vb + lp + u * 4);
            }
        }
        __syncthreads();

        // S[r][c] = sum_d Qs[r][d] * Kt[d][c]
        float s[4][4];
#pragma unroll
        for (int i = 0; i < 4; i++)
#pragma unroll
            for (int j = 0; j < 4; j++) s[i][j] = 0.f;
        for (int d = 0; d < 64; d += 4) {
            float a[4][4], kt[4][4];
#pragma unroll
            for (int i = 0; i < 4; i++) {
                float4 t4 = *(float4*)&Qs[ty * 4 + i][d];
                a[i][0] = t4.x; a[i][1] = t4.y; a[i][2] = t4.z; a[i][3] = t4.w;
            }
#pragma unroll
            for (int u = 0; u < 4; u++) {
                float4 t4 = *(float4*)&KPs[d + u][tx * 4];
                kt[u][0] = t4.x; kt[u][1] = t4.y; kt[u][2] = t4.z; kt[u][3] = t4.w;
            }
#pragma unroll
            for (int i = 0; i < 4; i++)
#pragma unroll
                for (int j = 0; j < 4; j++)
                    s[i][j] += a[i][0] * kt[0][j] + a[i][1] * kt[1][j]
                             + a[i][2] * kt[2][j] + a[i][3] * kt[3][j];
        }

        // online softmax update
        float p[4][4];
#pragma unroll
        for (int i = 0; i < 4; i++) {
            float mc = fmaxf(fmaxf(s[i][0], s[i][1]), fmaxf(s[i][2], s[i][3]));
#pragma unroll
            for (int mask = 1; mask < 16; mask <<= 1) mc = fmaxf(mc, __shfl_xor(mc, mask));
            float mn = fmaxf(m_prev[i], mc);
            float rs = 0.f;
#pragma unroll
            for (int j = 0; j < 4; j++) { p[i][j] = expf(s[i][j] - mn); rs += p[i][j]; }
#pragma unroll
            for (int mask = 1; mask < 16; mask <<= 1) rs += __shfl_xor(rs, mask);
            float alpha = expf(m_prev[i] - mn);
            lsum[i] = lsum[i] * alpha + rs;
#pragma unroll
            for (int j = 0; j < 4; j++) acc[i][j] *= alpha;
            m_prev[i] = mn;
        }

        __syncthreads();   // everyone done reading K^T
#pragma unroll
        for (int i = 0; i < 4; i++)
            *(float4*)&KPs[ty * 4 + i][tx * 4] = make_float4(p[i][0], p[i][1], p[i][2], p[i][3]);
        __syncthreads();

        // O[r][d] += P[r][k] * V[k][d]
        for (int k = 0; k < 64; k += 4) {
            float pr[4][4], vv[4][4];
#pragma unroll
            for (int i = 0; i < 4; i++) {
                float4 t4 = *(float4*)&KPs[ty * 4 + i][k];
                pr[i][0] = t4.x; pr[i][1] = t4.y; pr[i][2] = t4.z; pr[i][3] = t4.w;
            }
#pragma unroll
            for (int u = 0; u < 4; u++) {
                float4 t4 = *(float4*)&Vs[k + u][tx * 4];
                vv[u][0] = t4.x; vv[u][1] = t4.y; vv[u][2] = t4.z; vv[u][3] = t4.w;
            }
#pragma unroll
            for (int i = 0; i < 4; i++)
#pragma unroll
                for (int j = 0; j < 4; j++)
                    acc[i][j] += pr[i][0] * vv[0][j] + pr[i][1] * vv[1][j]
                               + pr[i][2] * vv[2][j] + pr[i][3] * vv[3][j];
        }
    }

    // write O[token][h*64 + d]
#pragma unroll
    for (int i = 0; i < 4; i++) {
        float rinv = 1.f / lsum[i];
        size_t row = (size_t)(b * SEQ + q0 + ty * 4 + i);
        *(float4*)(O + row * DMODEL + h * DHEAD + tx * 4) =
            make_float4(acc[i][0] * rinv, acc[i][1] * rinv, acc[i][2] * rinv, acc[i][3] * rinv);
    }
}

// ---------------- mean pool over S: one block per batch, no atomics ----------------
__global__ __launch_bounds__(128) void pool_kernel(const float* __restrict__ X,
                                                   float* __restrict__ pooled) {
    int b = blockIdx.x;
    int d0 = threadIdx.x * 4;
    float4 acc = make_float4(0.f, 0.f, 0.f, 0.f);
    const float* base = X + (size_t)b * SEQ * DMODEL + d0;
    for (int s2 = 0; s2 < SEQ; s2 += 4) {
#pragma unroll
        for (int u = 0; u < 4; u++) {
            float4 v = *(const float4*)(base + (size_t)(s2 + u) * DMODEL);
            acc.x += v.x; acc.y += v.y; acc.z += v.z; acc.w += v.w;
        }
    }
    *(float4*)(pooled + b * DMODEL + d0) = acc;   // sums; scaled by 1/1024 in mlp
}

// ---------------- MLP head: relu(pooled @ fc1 + b1) @ fc2 + b2 ----------------
__global__ __launch_bounds__(256) void mlp_kernel(const float* __restrict__ pooled,
                                                  const float* __restrict__ fc1_w,
                                                  const float* __restrict__ fc1_b,
                                                  const float* __restrict__ fc2_w,
                                                  const float* __restrict__ fc2_b,
                                                  float* __restrict__ out) {
    __shared__ float p[DMODEL];
    __shared__ float hbuf[FFDIM];
    __shared__ float red[NCLS][256];
    int b = blockIdx.x;
    int tid = threadIdx.x;
    for (int i = tid; i < DMODEL; i += 256) p[i] = pooled[b * DMODEL + i] * (1.f / 1024.f);
    __syncthreads();
    for (int ff = tid; ff < FFDIM; ff += 256) {
        float acc = fc1_b[ff];
        for (int k = 0; k < DMODEL; k++) acc += p[k] * fc1_w[(size_t)k * FFDIM + ff];
        hbuf[ff] = fmaxf(acc, 0.f);
    }
    __syncthreads();
    float a6[NCLS];
#pragma unroll
    for (int c = 0; c < NCLS; c++) a6[c] = 0.f;
    for (int k = tid; k < FFDIM; k += 256) {
        float hv = hbuf[k];
#pragma unroll
        for (int c = 0; c < NCLS; c++) a6[c] += hv * fc2_w[k * NCLS + c];
    }
#pragma unroll
    for (int c = 0; c < NCLS; c++) red[c][tid] = a6[c];
    __syncthreads();
    if (tid < NCLS) {
        float s2 = 0.f;
        for (int i = 0; i < 256; i++) s2 += red[tid][i];
        out[b * NCLS + tid] = s2 + fc2_b[tid];
    }
}

extern "C" void kernel_launch(void* const* d_in, const int* in_sizes, int n_in,
                              void* d_out, int out_size, void* d_ws, size_t ws_size,
                              hipStream_t stream) {
    const int* tokens = (const int*)d_in[0];
    const float* emb = (const float*)d_in[1];
    const float* qkv_w = (const float*)d_in[2];   // [L][512][1536]
    const float* qkv_b = (const float*)d_in[3];   // [L][1536]
    const float* fc_w = (const float*)d_in[4];    // [L][512][512]
    const float* fc_b = (const float*)d_in[5];    // [L][512]
    const float* gamma = (const float*)d_in[6];
    const float* beta = (const float*)d_in[7];
    const float* fc1_w = (const float*)d_in[8];   // [512][2048]
    const float* fc1_b = (const float*)d_in[9];
    const float* fc2_w = (const float*)d_in[10];  // [2048][6]
    const float* fc2_b = (const float*)d_in[11];
    float* out = (float*)d_out;

    // ws layout: X (64MB) | pooled (64KB) | QKVc | Oc   — chunkB adapts to ws_size.
    float* X = (float*)d_ws;
    float* pooled = X + (size_t)BS_TOK * DMODEL;
    float* QKVc = pooled + BATCH * DMODEL;

    size_t fixed_bytes = ((size_t)BS_TOK * DMODEL + BATCH * DMODEL) * sizeof(float);
    size_t per_batch = (size_t)SEQ * (QKVW + DMODEL) * sizeof(float);  // 8 MB
    int chunkB = 1;
    for (int cb = 8; cb >= 1; cb >>= 1) {
        if (fixed_bytes + (size_t)cb * per_batch <= ws_size) { chunkB = cb; break; }
    }
    float* Oc = QKVc + (size_t)chunkB * SEQ * QKVW;
    int rows = chunkB * SEQ;
    int nchunks = BATCH / chunkB;

    embed_pe_kernel<<<BS_TOK, 128, 0, stream>>>(tokens, emb, X);

    for (int l = 0; l < NLAYER; l++) {
        for (int c = 0; c < nchunks; c++) {
            float* Xc = X + (size_t)c * rows * DMODEL;
            gemm_f32_kernel<<<dim3(QKVW / 128, rows / 128), 256, 0, stream>>>(
                Xc, qkv_w + (size_t)l * DMODEL * QKVW, qkv_b + (size_t)l * QKVW,
                QKVc, rows, QKVW, DMODEL);
            attn_kernel<<<dim3(SEQ / 64, chunkB * NHEAD), 256, 0, stream>>>(QKVc, Oc);
            proj_ln_kernel<<<rows / 32, 256, 0, stream>>>(
                Oc, fc_w + (size_t)l * DMODEL * DMODEL, fc_b + (size_t)l * DMODEL,
                gamma, beta, Xc);
        }
    }

    pool_kernel<<<BATCH, 128, 0, stream>>>(X, pooled);
    mlp_kernel<<<BATCH, 256, 0, stream>>>(pooled, fc1_w, fc1_b, fc2_w, fc2_b, out);
}

// Round 3
// 1953.230 us; speedup vs baseline: 4.9863x; 4.9863x over previous
//
#include <hip/hip_runtime.h>
#include <cmath>

#define BS_TOK 32768      // B*S
#define DMODEL 512
#define NHEAD 8
#define DHEAD 64
#define NLAYER 3
#define FFDIM 2048
#define NCLS 6
#define BATCH 32
#define SEQ 1024
#define QKVW 1536         // 3*D

typedef short short8 __attribute__((ext_vector_type(8)));
typedef float float4v __attribute__((ext_vector_type(4)));
#define MFMA_BF16 __builtin_amdgcn_mfma_f32_16x16x32_bf16

__device__ __forceinline__ unsigned short f2bf(float x) {
    unsigned int u = __float_as_uint(x);
    u = (u + 0x7fffu + ((u >> 16) & 1u)) >> 16;   // RNE
    return (unsigned short)u;
}

// ---------------- embedding + sinusoidal PE -> X fp32 + Xb bf16 ----------------
__global__ __launch_bounds__(128) void embed_pe_kernel(const int* __restrict__ tokens,
                                                       const float* __restrict__ emb,
                                                       float* __restrict__ X,
                                                       unsigned short* __restrict__ Xb) {
    int t = blockIdx.x;
    int pos = t & (SEQ - 1);
    int tok = tokens[t];
    int d0 = threadIdx.x * 4;
    float4 e = *(const float4*)(emb + (size_t)tok * DMODEL + d0);
    const float c = -9.210340371976184f / 512.0f;
    float div0 = expf((float)d0 * c);
    float div1 = expf((float)(d0 + 2) * c);
    float a0 = (float)pos * div0;
    float a1 = (float)pos * div1;
    e.x += sinf(a0); e.y += cosf(a0);
    e.z += sinf(a1); e.w += cosf(a1);
    *(float4*)(X + (size_t)t * DMODEL + d0) = e;
    *(ushort4*)(Xb + (size_t)t * DMODEL + d0) =
        make_ushort4(f2bf(e.x), f2bf(e.y), f2bf(e.z), f2bf(e.w));
}

// ---------------- transpose + convert: in f32 [R][C] -> out bf16 [C][R], z = batch ----------------
__global__ __launch_bounds__(256) void transcvt_kernel(const float* __restrict__ in,
                                                       unsigned short* __restrict__ out,
                                                       int R, int C) {
    __shared__ float t[32][33];
    size_t base = (size_t)blockIdx.z * R * C;
    int c0 = blockIdx.x * 32, r0 = blockIdx.y * 32;
    int tx = threadIdx.x & 31, ty = threadIdx.x >> 5;   // 32 x 8
#pragma unroll
    for (int i = 0; i < 4; i++)
        t[ty + i * 8][tx] = in[base + (size_t)(r0 + ty + i * 8) * C + c0 + tx];
    __syncthreads();
#pragma unroll
    for (int i = 0; i < 4; i++)
        out[base + (size_t)(c0 + ty + i * 8) * R + r0 + tx] = f2bf(t[tx][ty + i * 8]);
}

// ---------------- bf16 MFMA GEMM: C[M,N] = A[M,K]bf16 @ Bt[N,K]bf16^T + bias ----------------
// 128x128 tile, BK=32, 256 thr = 4 waves of 64x64. OUTBF16: bf16 vs f32 output.
template <int OUTBF16>
__global__ __launch_bounds__(256) void gemm_bf16_kernel(const unsigned short* __restrict__ A,
                                                        const unsigned short* __restrict__ Bt,
                                                        const float* __restrict__ bias,
                                                        void* __restrict__ Cout,
                                                        int M, int N, int K) {
    __shared__ unsigned short As[128 * 40];   // row stride 40 (pad) -> conflict-free b128
    __shared__ unsigned short Bs[128 * 40];
    int bm = blockIdx.y * 128, bn = blockIdx.x * 128;
    int tid = threadIdx.x;
    int w = tid >> 6, lane = tid & 63, l15 = lane & 15, quad = lane >> 4;
    int wm = (w & 1) * 64, wn = (w >> 1) * 64;

    float4v acc[4][4];
    float4v z = {0.f, 0.f, 0.f, 0.f};
#pragma unroll
    for (int i = 0; i < 4; i++)
#pragma unroll
        for (int j = 0; j < 4; j++) acc[i][j] = z;

    int r0 = tid >> 2, o0 = (tid & 3) * 8;          // chunk tid
    int r1 = (tid + 256) >> 2, o1 = (tid & 3) * 8;  // chunk tid+256

    for (int k0 = 0; k0 < K; k0 += 32) {
        __syncthreads();
        *(short8*)&As[r0 * 40 + o0] = *(const short8*)(A + (size_t)(bm + r0) * K + k0 + o0);
        *(short8*)&As[r1 * 40 + o1] = *(const short8*)(A + (size_t)(bm + r1) * K + k0 + o1);
        *(short8*)&Bs[r0 * 40 + o0] = *(const short8*)(Bt + (size_t)(bn + r0) * K + k0 + o0);
        *(short8*)&Bs[r1 * 40 + o1] = *(const short8*)(Bt + (size_t)(bn + r1) * K + k0 + o1);
        __syncthreads();
        short8 af[4], bf[4];
#pragma unroll
        for (int i = 0; i < 4; i++)
            af[i] = *(short8*)&As[(wm + i * 16 + l15) * 40 + quad * 8];
#pragma unroll
        for (int j = 0; j < 4; j++)
            bf[j] = *(short8*)&Bs[(wn + j * 16 + l15) * 40 + quad * 8];
#pragma unroll
        for (int i = 0; i < 4; i++)
#pragma unroll
            for (int j = 0; j < 4; j++)
                acc[i][j] = MFMA_BF16(af[i], bf[j], acc[i][j], 0, 0, 0);
    }

    float bj[4];
#pragma unroll
    for (int j = 0; j < 4; j++) bj[j] = bias[bn + wn + j * 16 + l15];

#pragma unroll
    for (int i = 0; i < 4; i++) {
#pragma unroll
        for (int r = 0; r < 4; r++) {
            size_t row = (size_t)(bm + wm + i * 16 + quad * 4 + r);
#pragma unroll
            for (int j = 0; j < 4; j++) {
                float v = acc[i][j][r] + bj[j];
                size_t col = bn + wn + j * 16 + l15;
                if (OUTBF16) ((unsigned short*)Cout)[row * N + col] = f2bf(v);
                else         ((float*)Cout)[row * N + col] = v;
            }
        }
    }
}

// ---------------- bf16 MFMA flash attention ----------------
// QKV bf16 [tok][1536]: head h -> h*192 + {q:0, k:64, v:128}. O bf16 [tok][512].
// Block: 4 waves, wave w owns 16 Q rows; Q-tile 64, K-tile 64.
__global__ __launch_bounds__(256) void attn_kernel(const unsigned short* __restrict__ QKV,
                                                   unsigned short* __restrict__ O) {
    __shared__ unsigned short Ks[64 * 72];    // K[kcol][d], stride 72
    __shared__ unsigned short Vst[64 * 72];   // V^T[d][k] with XOR-swizzled 16B chunks
    __shared__ unsigned short Ps[4 * 16 * 72];// per-wave P[qrow][k]
    int bh = blockIdx.y;
    int b = bh >> 3, h = bh & 7;
    int q0 = blockIdx.x * 64;
    int tid = threadIdx.x;
    int w = tid >> 6, lane = tid & 63, l15 = lane & 15, quad = lane >> 4;
    unsigned short* Psb = &Ps[w * 16 * 72];

    // Q fragments (A-operand layout: m=l15, k=quad*8+j), loaded once from global
    short8 qf0, qf1;
    {
        const unsigned short* qb =
            QKV + (size_t)(b * SEQ + q0 + w * 16 + l15) * QKVW + h * 192;
        qf0 = *(const short8*)(qb + quad * 8);
        qf1 = *(const short8*)(qb + 32 + quad * 8);
    }

    float mprev[4] = {-1e30f, -1e30f, -1e30f, -1e30f};
    float lsum[4] = {0.f, 0.f, 0.f, 0.f};
    float4v accO[4];
    float4v z = {0.f, 0.f, 0.f, 0.f};
#pragma unroll
    for (int dc = 0; dc < 4; dc++) accO[dc] = z;

    for (int jt = 0; jt < SEQ / 64; jt++) {
        __syncthreads();
        // stage K (row-major) and V (transposed + swizzled)
#pragma unroll
        for (int cc = 0; cc < 2; cc++) {
            int c = tid + cc * 256;
            int kr = c >> 3, o = (c & 7) * 8;
            const unsigned short* kb =
                QKV + (size_t)(b * SEQ + jt * 64 + kr) * QKVW + h * 192 + 64;
            *(short8*)&Ks[kr * 72 + o] = *(const short8*)(kb + o);
            short8 vv = *(const short8*)(kb + 64 + o);
            int col = (((kr >> 3) ^ (c & 7)) * 8) + (kr & 7);
#pragma unroll
            for (int u = 0; u < 8; u++)
                Vst[(o + u) * 72 + col] = ((unsigned short*)&vv)[u];
        }
        __syncthreads();

        // S tile: wave's 16 q-rows x 64 k-cols
        float4v sv[4];
#pragma unroll
        for (int jc = 0; jc < 4; jc++) {
            float4v s = z;
            short8 kf0 = *(short8*)&Ks[(jc * 16 + l15) * 72 + quad * 8];
            short8 kf1 = *(short8*)&Ks[(jc * 16 + l15) * 72 + 32 + quad * 8];
            s = MFMA_BF16(qf0, kf0, s, 0, 0, 0);
            s = MFMA_BF16(qf1, kf1, s, 0, 0, 0);
            sv[jc] = s;
        }

        // online softmax (row = quad*4+r; 16 lanes sharing quad hold its 64 cols)
        float alpha[4];
#pragma unroll
        for (int r = 0; r < 4; r++) {
            float mx = fmaxf(fmaxf(sv[0][r], sv[1][r]), fmaxf(sv[2][r], sv[3][r])) * 0.125f;
#pragma unroll
            for (int mask = 1; mask < 16; mask <<= 1) mx = fmaxf(mx, __shfl_xor(mx, mask));
            float mn = fmaxf(mprev[r], mx);
            float rs = 0.f;
#pragma unroll
            for (int jc = 0; jc < 4; jc++) {
                float p = expf(sv[jc][r] * 0.125f - mn);
                Psb[(quad * 4 + r) * 72 + jc * 16 + l15] = f2bf(p);
                rs += p;
            }
#pragma unroll
            for (int mask = 1; mask < 16; mask <<= 1) rs += __shfl_xor(rs, mask);
            alpha[r] = expf(mprev[r] - mn);
            lsum[r] = lsum[r] * alpha[r] + rs;
            mprev[r] = mn;
        }
#pragma unroll
        for (int dc = 0; dc < 4; dc++) {
            float4v a = accO[dc];
            a[0] *= alpha[0]; a[1] *= alpha[1]; a[2] *= alpha[2]; a[3] *= alpha[3];
            accO[dc] = a;
        }

        // P back as A-operand (wave-private LDS; in-order DS => no barrier)
        short8 pf0 = *(short8*)&Psb[l15 * 72 + quad * 8];
        short8 pf1 = *(short8*)&Psb[l15 * 72 + 32 + quad * 8];

        // PV: O[16 x 64d] += P[16 x 64k] * V[64k x 64d]
#pragma unroll
        for (int dc = 0; dc < 4; dc++) {
            int d = dc * 16 + l15;
            int sw = (d >> 3) & 7;
            short8 vf0 = *(short8*)&Vst[d * 72 + ((quad ^ sw) * 8)];
            short8 vf1 = *(short8*)&Vst[d * 72 + (((4 + quad) ^ sw) * 8)];
            accO[dc] = MFMA_BF16(pf0, vf0, accO[dc], 0, 0, 0);
            accO[dc] = MFMA_BF16(pf1, vf1, accO[dc], 0, 0, 0);
        }
    }

    // epilogue: O[tok][h*64+d] bf16
#pragma unroll
    for (int r = 0; r < 4; r++) {
        float rinv = 1.f / lsum[r];
        size_t row = (size_t)(b * SEQ + q0 + w * 16 + quad * 4 + r);
#pragma unroll
        for (int dc = 0; dc < 4; dc++)
            O[row * DMODEL + h * DHEAD + dc * 16 + l15] = f2bf(accO[dc][r] * rinv);
    }
}

// ---------------- residual + layernorm: one wave per row ----------------
__global__ __launch_bounds__(64) void ln_res_kernel(const float* __restrict__ Y,
                                                    const float* __restrict__ gamma,
                                                    const float* __restrict__ beta,
                                                    float* __restrict__ X,
                                                    unsigned short* __restrict__ Xb) {
    int t = blockIdx.x;
    int tid = threadIdx.x;
    const float* y = Y + (size_t)t * DMODEL;
    float* x = X + (size_t)t * DMODEL;
    float o[8];
    {
        float4 y0 = *(const float4*)(y + tid * 8);
        float4 y1 = *(const float4*)(y + tid * 8 + 4);
        float4 x0 = *(const float4*)(x + tid * 8);
        float4 x1 = *(const float4*)(x + tid * 8 + 4);
        o[0] = y0.x + x0.x; o[1] = y0.y + x0.y; o[2] = y0.z + x0.z; o[3] = y0.w + x0.w;
        o[4] = y1.x + x1.x; o[5] = y1.y + x1.y; o[6] = y1.z + x1.z; o[7] = y1.w + x1.w;
    }
    float s = 0.f, sq = 0.f;
#pragma unroll
    for (int j = 0; j < 8; j++) { s += o[j]; sq += o[j] * o[j]; }
#pragma unroll
    for (int mask = 1; mask < 64; mask <<= 1) {
        s += __shfl_xor(s, mask);
        sq += __shfl_xor(sq, mask);
    }
    float mean = s * (1.f / 512.f);
    float var = sq * (1.f / 512.f) - mean * mean;
    float rstd = rsqrtf(var + 1e-5f);
    float4 g0 = *(const float4*)(gamma + tid * 8);
    float4 g1 = *(const float4*)(gamma + tid * 8 + 4);
    float4 b0 = *(const float4*)(beta + tid * 8);
    float4 b1 = *(const float4*)(beta + tid * 8 + 4);
    float n[8];
    n[0] = (o[0]-mean)*rstd*g0.x + b0.x; n[1] = (o[1]-mean)*rstd*g0.y + b0.y;
    n[2] = (o[2]-mean)*rstd*g0.z + b0.z; n[3] = (o[3]-mean)*rstd*g0.w + b0.w;
    n[4] = (o[4]-mean)*rstd*g1.x + b1.x; n[5] = (o[5]-mean)*rstd*g1.y + b1.y;
    n[6] = (o[6]-mean)*rstd*g1.z + b1.z; n[7] = (o[7]-mean)*rstd*g1.w + b1.w;
    *(float4*)(x + tid * 8) = make_float4(n[0], n[1], n[2], n[3]);
    *(float4*)(x + tid * 8 + 4) = make_float4(n[4], n[5], n[6], n[7]);
    unsigned short* xb = Xb + (size_t)t * DMODEL + tid * 8;
    *(ushort4*)xb = make_ushort4(f2bf(n[0]), f2bf(n[1]), f2bf(n[2]), f2bf(n[3]));
    *(ushort4*)(xb + 4) = make_ushort4(f2bf(n[4]), f2bf(n[5]), f2bf(n[6]), f2bf(n[7]));
}

// ---------------- mean pool over S ----------------
__global__ __launch_bounds__(128) void pool_kernel(const float* __restrict__ X,
                                                   float* __restrict__ pooled) {
    int b = blockIdx.x;
    int d0 = threadIdx.x * 4;
    float4 acc = make_float4(0.f, 0.f, 0.f, 0.f);
    const float* base = X + (size_t)b * SEQ * DMODEL + d0;
    for (int s2 = 0; s2 < SEQ; s2 += 4) {
#pragma unroll
        for (int u = 0; u < 4; u++) {
            float4 v = *(const float4*)(base + (size_t)(s2 + u) * DMODEL);
            acc.x += v.x; acc.y += v.y; acc.z += v.z; acc.w += v.w;
        }
    }
    *(float4*)(pooled + b * DMODEL + d0) = acc;
}

// ---------------- MLP head ----------------
__global__ __launch_bounds__(256) void mlp_kernel(const float* __restrict__ pooled,
                                                  const float* __restrict__ fc1_w,
                                                  const float* __restrict__ fc1_b,
                                                  const float* __restrict__ fc2_w,
                                                  const float* __restrict__ fc2_b,
                                                  float* __restrict__ out) {
    __shared__ float p[DMODEL];
    __shared__ float hbuf[FFDIM];
    __shared__ float red[NCLS][256];
    int b = blockIdx.x;
    int tid = threadIdx.x;
    for (int i = tid; i < DMODEL; i += 256) p[i] = pooled[b * DMODEL + i] * (1.f / 1024.f);
    __syncthreads();
    for (int ff = tid; ff < FFDIM; ff += 256) {
        float acc = fc1_b[ff];
        for (int k = 0; k < DMODEL; k++) acc += p[k] * fc1_w[(size_t)k * FFDIM + ff];
        hbuf[ff] = fmaxf(acc, 0.f);
    }
    __syncthreads();
    float a6[NCLS];
#pragma unroll
    for (int c = 0; c < NCLS; c++) a6[c] = 0.f;
    for (int k = tid; k < FFDIM; k += 256) {
        float hv = hbuf[k];
#pragma unroll
        for (int c = 0; c < NCLS; c++) a6[c] += hv * fc2_w[k * NCLS + c];
    }
#pragma unroll
    for (int c = 0; c < NCLS; c++) red[c][tid] = a6[c];
    __syncthreads();
    if (tid < NCLS) {
        float s2 = 0.f;
        for (int i = 0; i < 256; i++) s2 += red[tid][i];
        out[b * NCLS + tid] = s2 + fc2_b[tid];
    }
}

extern "C" void kernel_launch(void* const* d_in, const int* in_sizes, int n_in,
                              void* d_out, int out_size, void* d_ws, size_t ws_size,
                              hipStream_t stream) {
    const int* tokens = (const int*)d_in[0];
    const float* emb = (const float*)d_in[1];
    const float* qkv_w = (const float*)d_in[2];   // [L][512][1536]
    const float* qkv_b = (const float*)d_in[3];
    const float* fc_w = (const float*)d_in[4];    // [L][512][512]
    const float* fc_b = (const float*)d_in[5];
    const float* gamma = (const float*)d_in[6];
    const float* beta = (const float*)d_in[7];
    const float* fc1_w = (const float*)d_in[8];
    const float* fc1_b = (const float*)d_in[9];
    const float* fc2_w = (const float*)d_in[10];
    const float* fc2_b = (const float*)d_in[11];
    float* out = (float*)d_out;

    // workspace layout
    char* p = (char*)d_ws;
    float* X = (float*)p;                 p += (size_t)BS_TOK * DMODEL * 4;      // 64 MB
    unsigned short* Xb = (unsigned short*)p; p += (size_t)BS_TOK * DMODEL * 2;   // 32 MB
    float* pooled = (float*)p;            p += (size_t)BATCH * DMODEL * 4;
    unsigned short* qkv_wbt = (unsigned short*)p; p += (size_t)NLAYER * QKVW * DMODEL * 2;
    unsigned short* fc_wt = (unsigned short*)p;   p += (size_t)NLAYER * DMODEL * DMODEL * 2;
    size_t fixed_bytes = (size_t)(p - (char*)d_ws);
    size_t per_batch = (size_t)SEQ * (QKVW * 2 + DMODEL * 2 + DMODEL * 4);  // 6 MB
    int chunkB = 1;
    for (int cb = 8; cb >= 1; cb >>= 1)
        if (fixed_bytes + (size_t)cb * per_batch <= ws_size) { chunkB = cb; break; }
    unsigned short* QKVc = (unsigned short*)p;   p += (size_t)chunkB * SEQ * QKVW * 2;
    unsigned short* Oc = (unsigned short*)p;     p += (size_t)chunkB * SEQ * DMODEL * 2;
    float* Y = (float*)p;
    int rows = chunkB * SEQ;
    int nchunks = BATCH / chunkB;

    embed_pe_kernel<<<BS_TOK, 128, 0, stream>>>(tokens, emb, X, Xb);
    transcvt_kernel<<<dim3(QKVW / 32, DMODEL / 32, NLAYER), 256, 0, stream>>>(
        qkv_w, qkv_wbt, DMODEL, QKVW);
    transcvt_kernel<<<dim3(DMODEL / 32, DMODEL / 32, NLAYER), 256, 0, stream>>>(
        fc_w, fc_wt, DMODEL, DMODEL);

    for (int l = 0; l < NLAYER; l++) {
        for (int c = 0; c < nchunks; c++) {
            unsigned short* Xbc = Xb + (size_t)c * rows * DMODEL;
            float* Xc = X + (size_t)c * rows * DMODEL;
            gemm_bf16_kernel<1><<<dim3(QKVW / 128, rows / 128), 256, 0, stream>>>(
                Xbc, qkv_wbt + (size_t)l * QKVW * DMODEL, qkv_b + (size_t)l * QKVW,
                QKVc, rows, QKVW, DMODEL);
            attn_kernel<<<dim3(SEQ / 64, chunkB * NHEAD), 256, 0, stream>>>(QKVc, Oc);
            gemm_bf16_kernel<0><<<dim3(DMODEL / 128, rows / 128), 256, 0, stream>>>(
                Oc, fc_wt + (size_t)l * DMODEL * DMODEL, fc_b + (size_t)l * DMODEL,
                Y, rows, DMODEL, DMODEL);
            ln_res_kernel<<<rows, 64, 0, stream>>>(Y, gamma, beta, Xc, Xbc);
        }
    }

    pool_kernel<<<BATCH, 128, 0, stream>>>(X, pooled);
    mlp_kernel<<<BATCH, 256, 0, stream>>>(pooled, fc1_w, fc1_b, fc2_w, fc2_b, out);
}

// Round 4
// 1337.900 us; speedup vs baseline: 7.2796x; 1.4599x over previous
//
#include <hip/hip_runtime.h>
#include <cmath>

#define BS_TOK 32768      // B*S
#define DMODEL 512
#define NHEAD 8
#define DHEAD 64
#define NLAYER 3
#define FFDIM 2048
#define NCLS 6
#define BATCH 32
#define SEQ 1024
#define QKVW 1536         // 3*D

typedef short short8 __attribute__((ext_vector_type(8)));
typedef float float4v __attribute__((ext_vector_type(4)));
#define MFMA_BF16 __builtin_amdgcn_mfma_f32_16x16x32_bf16

__device__ __forceinline__ unsigned short f2bf(float x) {
    unsigned int u = __float_as_uint(x);
    u = (u + 0x7fffu + ((u >> 16) & 1u)) >> 16;   // RNE
    return (unsigned short)u;
}

// ---------------- embedding + sinusoidal PE -> X fp32 + Xb bf16 ----------------
__global__ __launch_bounds__(128) void embed_pe_kernel(const int* __restrict__ tokens,
                                                       const float* __restrict__ emb,
                                                       float* __restrict__ X,
                                                       unsigned short* __restrict__ Xb) {
    int t = blockIdx.x;
    int pos = t & (SEQ - 1);
    int tok = tokens[t];
    int d0 = threadIdx.x * 4;
    float4 e = *(const float4*)(emb + (size_t)tok * DMODEL + d0);
    const float c = -9.210340371976184f / 512.0f;
    float div0 = expf((float)d0 * c);
    float div1 = expf((float)(d0 + 2) * c);
    float a0 = (float)pos * div0;
    float a1 = (float)pos * div1;
    e.x += sinf(a0); e.y += cosf(a0);
    e.z += sinf(a1); e.w += cosf(a1);
    *(float4*)(X + (size_t)t * DMODEL + d0) = e;
    *(ushort4*)(Xb + (size_t)t * DMODEL + d0) =
        make_ushort4(f2bf(e.x), f2bf(e.y), f2bf(e.z), f2bf(e.w));
}

// ---------------- transpose + convert: in f32 [R][C] -> out bf16 [C][R], z = layer ----------------
__global__ __launch_bounds__(256) void transcvt_kernel(const float* __restrict__ in,
                                                       unsigned short* __restrict__ out,
                                                       int R, int C) {
    __shared__ float t[32][33];
    size_t base = (size_t)blockIdx.z * R * C;
    int c0 = blockIdx.x * 32, r0 = blockIdx.y * 32;
    int tx = threadIdx.x & 31, ty = threadIdx.x >> 5;   // 32 x 8
#pragma unroll
    for (int i = 0; i < 4; i++)
        t[ty + i * 8][tx] = in[base + (size_t)(r0 + ty + i * 8) * C + c0 + tx];
    __syncthreads();
#pragma unroll
    for (int i = 0; i < 4; i++)
        out[base + (size_t)(c0 + ty + i * 8) * R + r0 + tx] = f2bf(t[tx][ty + i * 8]);
}

// ---------------- bf16 MFMA GEMM (QKV): C[M,N]bf16 = A[M,K]bf16 @ Bt[N,K]^T + bias ----------------
__global__ __launch_bounds__(256) void gemm_bf16_kernel(const unsigned short* __restrict__ A,
                                                        const unsigned short* __restrict__ Bt,
                                                        const float* __restrict__ bias,
                                                        unsigned short* __restrict__ Cout,
                                                        int M, int N, int K) {
    __shared__ unsigned short As[128 * 40];
    __shared__ unsigned short Bs[128 * 40];
    int bm = blockIdx.y * 128, bn = blockIdx.x * 128;
    int tid = threadIdx.x;
    int w = tid >> 6, lane = tid & 63, l15 = lane & 15, quad = lane >> 4;
    int wm = (w & 1) * 64, wn = (w >> 1) * 64;

    float4v acc[4][4];
    float4v z = {0.f, 0.f, 0.f, 0.f};
#pragma unroll
    for (int i = 0; i < 4; i++)
#pragma unroll
        for (int j = 0; j < 4; j++) acc[i][j] = z;

    int r0 = tid >> 2, o0 = (tid & 3) * 8;
    int r1 = (tid + 256) >> 2, o1 = (tid & 3) * 8;

    for (int k0 = 0; k0 < K; k0 += 32) {
        __syncthreads();
        *(short8*)&As[r0 * 40 + o0] = *(const short8*)(A + (size_t)(bm + r0) * K + k0 + o0);
        *(short8*)&As[r1 * 40 + o1] = *(const short8*)(A + (size_t)(bm + r1) * K + k0 + o1);
        *(short8*)&Bs[r0 * 40 + o0] = *(const short8*)(Bt + (size_t)(bn + r0) * K + k0 + o0);
        *(short8*)&Bs[r1 * 40 + o1] = *(const short8*)(Bt + (size_t)(bn + r1) * K + k0 + o1);
        __syncthreads();
        short8 af[4], bf[4];
#pragma unroll
        for (int i = 0; i < 4; i++)
            af[i] = *(short8*)&As[(wm + i * 16 + l15) * 40 + quad * 8];
#pragma unroll
        for (int j = 0; j < 4; j++)
            bf[j] = *(short8*)&Bs[(wn + j * 16 + l15) * 40 + quad * 8];
#pragma unroll
        for (int i = 0; i < 4; i++)
#pragma unroll
            for (int j = 0; j < 4; j++)
                acc[i][j] = MFMA_BF16(af[i], bf[j], acc[i][j], 0, 0, 0);
    }

    float bj[4];
#pragma unroll
    for (int j = 0; j < 4; j++) bj[j] = bias[bn + wn + j * 16 + l15];

#pragma unroll
    for (int i = 0; i < 4; i++)
#pragma unroll
        for (int r = 0; r < 4; r++) {
            size_t row = (size_t)(bm + wm + i * 16 + quad * 4 + r);
#pragma unroll
            for (int j = 0; j < 4; j++)
                Cout[row * N + bn + wn + j * 16 + l15] = f2bf(acc[i][j][r] + bj[j]);
        }
}

// ---------------- bf16 MFMA flash attention, Q-tile 128 ----------------
// QKV bf16 [tok][1536]: head h -> h*192 + {q:0,k:64,v:128}. Wave owns 32 Q rows.
__global__ __launch_bounds__(256) void attn_kernel(const unsigned short* __restrict__ QKV,
                                                   unsigned short* __restrict__ O) {
    __shared__ unsigned short Ks[64 * 72];
    __shared__ unsigned short Vst[64 * 72];
    __shared__ unsigned short Ps[4 * 32 * 72];
    int bh = blockIdx.y;
    int b = bh >> 3, h = bh & 7;
    int q0 = blockIdx.x * 128;
    int tid = threadIdx.x;
    int w = tid >> 6, lane = tid & 63, l15 = lane & 15, quad = lane >> 4;
    unsigned short* Psb = &Ps[w * 32 * 72];

    short8 qf[2][2];
#pragma unroll
    for (int i = 0; i < 2; i++) {
        const unsigned short* qb =
            QKV + (size_t)(b * SEQ + q0 + w * 32 + i * 16 + l15) * QKVW + h * 192;
        qf[i][0] = *(const short8*)(qb + quad * 8);
        qf[i][1] = *(const short8*)(qb + 32 + quad * 8);
    }

    float mprev[2][4], lsum[2][4];
    float4v accO[2][4];
    float4v z = {0.f, 0.f, 0.f, 0.f};
#pragma unroll
    for (int i = 0; i < 2; i++)
#pragma unroll
        for (int r = 0; r < 4; r++) { mprev[i][r] = -1e30f; lsum[i][r] = 0.f; }
#pragma unroll
    for (int i = 0; i < 2; i++)
#pragma unroll
        for (int dc = 0; dc < 4; dc++) accO[i][dc] = z;

    for (int jt = 0; jt < SEQ / 64; jt++) {
        __syncthreads();
#pragma unroll
        for (int cc = 0; cc < 2; cc++) {
            int c = tid + cc * 256;
            int kr = c >> 3, o = (c & 7) * 8;
            const unsigned short* kb =
                QKV + (size_t)(b * SEQ + jt * 64 + kr) * QKVW + h * 192 + 64;
            *(short8*)&Ks[kr * 72 + o] = *(const short8*)(kb + o);
            short8 vv = *(const short8*)(kb + 64 + o);
            int col = (((kr >> 3) ^ (c & 7)) * 8) + (kr & 7);
#pragma unroll
            for (int u = 0; u < 8; u++)
                Vst[(o + u) * 72 + col] = ((unsigned short*)&vv)[u];
        }
        __syncthreads();

        // S: 32 q-rows x 64 k-cols per wave (K frags reused across both row-halves)
        float4v sv[2][4];
#pragma unroll
        for (int jc = 0; jc < 4; jc++) {
            short8 kf0 = *(short8*)&Ks[(jc * 16 + l15) * 72 + quad * 8];
            short8 kf1 = *(short8*)&Ks[(jc * 16 + l15) * 72 + 32 + quad * 8];
#pragma unroll
            for (int i = 0; i < 2; i++) {
                float4v s = MFMA_BF16(qf[i][0], kf0, z, 0, 0, 0);
                sv[i][jc] = MFMA_BF16(qf[i][1], kf1, s, 0, 0, 0);
            }
        }

        // online softmax per row (row = i*16 + quad*4 + r)
#pragma unroll
        for (int i = 0; i < 2; i++) {
            float alpha[4];
#pragma unroll
            for (int r = 0; r < 4; r++) {
                float mx = fmaxf(fmaxf(sv[i][0][r], sv[i][1][r]),
                                 fmaxf(sv[i][2][r], sv[i][3][r])) * 0.125f;
#pragma unroll
                for (int mask = 1; mask < 16; mask <<= 1) mx = fmaxf(mx, __shfl_xor(mx, mask));
                float mn = fmaxf(mprev[i][r], mx);
                float rs = 0.f;
#pragma unroll
                for (int jc = 0; jc < 4; jc++) {
                    float p = __expf(sv[i][jc][r] * 0.125f - mn);
                    Psb[(i * 16 + quad * 4 + r) * 72 + jc * 16 + l15] = f2bf(p);
                    rs += p;
                }
#pragma unroll
                for (int mask = 1; mask < 16; mask <<= 1) rs += __shfl_xor(rs, mask);
                alpha[r] = __expf(mprev[i][r] - mn);
                lsum[i][r] = lsum[i][r] * alpha[r] + rs;
                mprev[i][r] = mn;
            }
#pragma unroll
            for (int dc = 0; dc < 4; dc++) {
                float4v a = accO[i][dc];
                a[0] *= alpha[0]; a[1] *= alpha[1]; a[2] *= alpha[2]; a[3] *= alpha[3];
                accO[i][dc] = a;
            }
        }

        // P frags (wave-private LDS, in-order DS => no barrier)
        short8 pf[2][2];
#pragma unroll
        for (int i = 0; i < 2; i++) {
            pf[i][0] = *(short8*)&Psb[(i * 16 + l15) * 72 + quad * 8];
            pf[i][1] = *(short8*)&Psb[(i * 16 + l15) * 72 + 32 + quad * 8];
        }

        // PV (V frags reused across both row-halves)
#pragma unroll
        for (int dc = 0; dc < 4; dc++) {
            int d = dc * 16 + l15;
            int sw = (d >> 3) & 7;
            short8 vf0 = *(short8*)&Vst[d * 72 + ((quad ^ sw) * 8)];
            short8 vf1 = *(short8*)&Vst[d * 72 + (((4 + quad) ^ sw) * 8)];
#pragma unroll
            for (int i = 0; i < 2; i++) {
                accO[i][dc] = MFMA_BF16(pf[i][0], vf0, accO[i][dc], 0, 0, 0);
                accO[i][dc] = MFMA_BF16(pf[i][1], vf1, accO[i][dc], 0, 0, 0);
            }
        }
    }

#pragma unroll
    for (int i = 0; i < 2; i++)
#pragma unroll
        for (int r = 0; r < 4; r++) {
            float rinv = 1.f / lsum[i][r];
            size_t row = (size_t)(b * SEQ + q0 + w * 32 + i * 16 + quad * 4 + r);
#pragma unroll
            for (int dc = 0; dc < 4; dc++)
                O[row * DMODEL + h * DHEAD + dc * 16 + l15] = f2bf(accO[i][dc][r] * rinv);
        }
}

// ---------------- fused out-proj + bias + residual + LayerNorm ----------------
// 32 rows x full 512 cols per block; wave w owns cols [w*128, w*128+128).
// Cross-wave LN reduction via LDS; writes X f32 + Xb bf16 in place. No Y buffer.
__global__ __launch_bounds__(256) void proj_ln_kernel(const unsigned short* __restrict__ A,
                                                      const unsigned short* __restrict__ Bt,
                                                      const float* __restrict__ bias,
                                                      const float* __restrict__ gamma,
                                                      const float* __restrict__ beta,
                                                      float* __restrict__ X,
                                                      unsigned short* __restrict__ Xb) {
    __shared__ unsigned short As[32 * 40];
    __shared__ unsigned short Bs[512 * 40];
    __shared__ float redS[4][32], redQ[4][32];
    int bm = blockIdx.x * 32;
    int tid = threadIdx.x;
    int w = tid >> 6, lane = tid & 63, l15 = lane & 15, quad = lane >> 4;
    int wn = w * 128;

    float4v acc[2][8];
    float4v z = {0.f, 0.f, 0.f, 0.f};
#pragma unroll
    for (int i = 0; i < 2; i++)
#pragma unroll
        for (int j = 0; j < 8; j++) acc[i][j] = z;

    for (int k0 = 0; k0 < DMODEL; k0 += 32) {
        __syncthreads();
        if (tid < 128) {
            int r = tid >> 2, o = (tid & 3) * 8;
            *(short8*)&As[r * 40 + o] = *(const short8*)(A + (size_t)(bm + r) * DMODEL + k0 + o);
        }
#pragma unroll
        for (int u = 0; u < 8; u++) {
            int c = tid + u * 256;
            int r = c >> 2, o = (c & 3) * 8;
            *(short8*)&Bs[r * 40 + o] = *(const short8*)(Bt + (size_t)r * DMODEL + k0 + o);
        }
        __syncthreads();
        short8 af[2];
#pragma unroll
        for (int i = 0; i < 2; i++)
            af[i] = *(short8*)&As[(i * 16 + l15) * 40 + quad * 8];
#pragma unroll
        for (int j = 0; j < 8; j++) {
            short8 bf = *(short8*)&Bs[(wn + j * 16 + l15) * 40 + quad * 8];
            acc[0][j] = MFMA_BF16(af[0], bf, acc[0][j], 0, 0, 0);
            acc[1][j] = MFMA_BF16(af[1], bf, acc[1][j], 0, 0, 0);
        }
    }

    float bj[8], g[8], be[8];
#pragma unroll
    for (int j = 0; j < 8; j++) {
        int col = wn + j * 16 + l15;
        bj[j] = bias[col]; g[j] = gamma[col]; be[j] = beta[col];
    }

    float o[2][4][8];
#pragma unroll
    for (int i = 0; i < 2; i++)
#pragma unroll
        for (int r = 0; r < 4; r++) {
            int lrow = i * 16 + quad * 4 + r;
            size_t row = (size_t)(bm + lrow);
            float ss = 0.f, qq = 0.f;
#pragma unroll
            for (int j = 0; j < 8; j++) {
                float v = acc[i][j][r] + bj[j] + X[row * DMODEL + wn + j * 16 + l15];
                o[i][r][j] = v; ss += v; qq += v * v;
            }
#pragma unroll
            for (int mask = 1; mask < 16; mask <<= 1) {
                ss += __shfl_xor(ss, mask);
                qq += __shfl_xor(qq, mask);
            }
            if (l15 == 0) { redS[w][lrow] = ss; redQ[w][lrow] = qq; }
        }
    __syncthreads();
#pragma unroll
    for (int i = 0; i < 2; i++)
#pragma unroll
        for (int r = 0; r < 4; r++) {
            int lrow = i * 16 + quad * 4 + r;
            float S = redS[0][lrow] + redS[1][lrow] + redS[2][lrow] + redS[3][lrow];
            float Q = redQ[0][lrow] + redQ[1][lrow] + redQ[2][lrow] + redQ[3][lrow];
            float mean = S * (1.f / 512.f);
            float var = Q * (1.f / 512.f) - mean * mean;
            float rstd = rsqrtf(var + 1e-5f);
            size_t row = (size_t)(bm + lrow);
#pragma unroll
            for (int j = 0; j < 8; j++) {
                float n = (o[i][r][j] - mean) * rstd * g[j] + be[j];
                X[row * DMODEL + wn + j * 16 + l15] = n;
                Xb[row * DMODEL + wn + j * 16 + l15] = f2bf(n);
            }
        }
}

// ---------------- pooled zero + two-stage mean pool ----------------
__global__ __launch_bounds__(256) void zero_kernel(float* __restrict__ p) {
    p[blockIdx.x * 256 + threadIdx.x] = 0.f;
}
__global__ __launch_bounds__(128) void pool_kernel(const float* __restrict__ X,
                                                   float* __restrict__ pooled) {
    int b = blockIdx.x, ch = blockIdx.y;   // 16 chunks of 64 rows
    int d0 = threadIdx.x * 4;
    float4 acc = make_float4(0.f, 0.f, 0.f, 0.f);
    const float* base = X + (size_t)(b * SEQ + ch * 64) * DMODEL + d0;
    for (int s2 = 0; s2 < 64; s2++) {
        float4 v = *(const float4*)(base + (size_t)s2 * DMODEL);
        acc.x += v.x; acc.y += v.y; acc.z += v.z; acc.w += v.w;
    }
    atomicAdd(pooled + b * DMODEL + d0 + 0, acc.x);
    atomicAdd(pooled + b * DMODEL + d0 + 1, acc.y);
    atomicAdd(pooled + b * DMODEL + d0 + 2, acc.z);
    atomicAdd(pooled + b * DMODEL + d0 + 3, acc.w);
}

// ---------------- MLP head: fc1 spread over 256 blocks, fc2 per batch ----------------
__global__ __launch_bounds__(256) void fc1_kernel(const float* __restrict__ pooled,
                                                  const float* __restrict__ fc1_w,
                                                  const float* __restrict__ fc1_b,
                                                  float* __restrict__ h) {
    __shared__ float p[DMODEL];
    int ffc = blockIdx.x, b = blockIdx.y;
    int tid = threadIdx.x;
    p[tid] = pooled[b * DMODEL + tid] * (1.f / 1024.f);
    p[tid + 256] = pooled[b * DMODEL + tid + 256] * (1.f / 1024.f);
    __syncthreads();
    int ff = ffc * 256 + tid;
    float acc = fc1_b[ff];
    for (int k = 0; k < DMODEL; k++) acc += p[k] * fc1_w[(size_t)k * FFDIM + ff];
    h[(size_t)b * FFDIM + ff] = fmaxf(acc, 0.f);
}

__global__ __launch_bounds__(256) void fc2_kernel(const float* __restrict__ h,
                                                  const float* __restrict__ fc2_w,
                                                  const float* __restrict__ fc2_b,
                                                  float* __restrict__ out) {
    __shared__ float red[NCLS][256];
    int b = blockIdx.x, tid = threadIdx.x;
    float a[NCLS];
#pragma unroll
    for (int c = 0; c < NCLS; c++) a[c] = 0.f;
    int k0 = tid * 8;
#pragma unroll
    for (int u = 0; u < 8; u++) {
        float hv = h[(size_t)b * FFDIM + k0 + u];
#pragma unroll
        for (int c = 0; c < NCLS; c++) a[c] += hv * fc2_w[(k0 + u) * NCLS + c];
    }
#pragma unroll
    for (int c = 0; c < NCLS; c++) red[c][tid] = a[c];
    __syncthreads();
    if (tid < NCLS) {
        float s = 0.f;
        for (int i = 0; i < 256; i++) s += red[tid][i];
        out[b * NCLS + tid] = s + fc2_b[tid];
    }
}

extern "C" void kernel_launch(void* const* d_in, const int* in_sizes, int n_in,
                              void* d_out, int out_size, void* d_ws, size_t ws_size,
                              hipStream_t stream) {
    const int* tokens = (const int*)d_in[0];
    const float* emb = (const float*)d_in[1];
    const float* qkv_w = (const float*)d_in[2];
    const float* qkv_b = (const float*)d_in[3];
    const float* fc_w = (const float*)d_in[4];
    const float* fc_b = (const float*)d_in[5];
    const float* gamma = (const float*)d_in[6];
    const float* beta = (const float*)d_in[7];
    const float* fc1_w = (const float*)d_in[8];
    const float* fc1_b = (const float*)d_in[9];
    const float* fc2_w = (const float*)d_in[10];
    const float* fc2_b = (const float*)d_in[11];
    float* out = (float*)d_out;

    char* p = (char*)d_ws;
    float* X = (float*)p;                         p += (size_t)BS_TOK * DMODEL * 4;  // 64 MB
    unsigned short* Xb = (unsigned short*)p;      p += (size_t)BS_TOK * DMODEL * 2;  // 32 MB
    float* pooled = (float*)p;                    p += (size_t)BATCH * DMODEL * 4;
    float* hbuf = (float*)p;                      p += (size_t)BATCH * FFDIM * 4;
    unsigned short* qkv_wbt = (unsigned short*)p; p += (size_t)NLAYER * QKVW * DMODEL * 2;
    unsigned short* fc_wt = (unsigned short*)p;   p += (size_t)NLAYER * DMODEL * DMODEL * 2;
    size_t fixed_bytes = (size_t)(p - (char*)d_ws);
    size_t per_batch = (size_t)SEQ * (QKVW + DMODEL) * 2;   // 4 MB (QKVc + Oc, no Y)
    int chunkB = 1;
    for (int cb = 32; cb >= 1; cb >>= 1)
        if (fixed_bytes + (size_t)cb * per_batch <= ws_size) { chunkB = cb; break; }
    unsigned short* QKVc = (unsigned short*)p;    p += (size_t)chunkB * SEQ * QKVW * 2;
    unsigned short* Oc = (unsigned short*)p;
    int rows = chunkB * SEQ;
    int nchunks = BATCH / chunkB;

    embed_pe_kernel<<<BS_TOK, 128, 0, stream>>>(tokens, emb, X, Xb);
    transcvt_kernel<<<dim3(QKVW / 32, DMODEL / 32, NLAYER), 256, 0, stream>>>(
        qkv_w, qkv_wbt, DMODEL, QKVW);
    transcvt_kernel<<<dim3(DMODEL / 32, DMODEL / 32, NLAYER), 256, 0, stream>>>(
        fc_w, fc_wt, DMODEL, DMODEL);

    for (int l = 0; l < NLAYER; l++) {
        for (int c = 0; c < nchunks; c++) {
            unsigned short* Xbc = Xb + (size_t)c * rows * DMODEL;
            float* Xc = X + (size_t)c * rows * DMODEL;
            gemm_bf16_kernel<<<dim3(QKVW / 128, rows / 128), 256, 0, stream>>>(
                Xbc, qkv_wbt + (size_t)l * QKVW * DMODEL, qkv_b + (size_t)l * QKVW,
                QKVc, rows, QKVW, DMODEL);
            attn_kernel<<<dim3(SEQ / 128, chunkB * NHEAD), 256, 0, stream>>>(QKVc, Oc);
            proj_ln_kernel<<<rows / 32, 256, 0, stream>>>(
                Oc, fc_wt + (size_t)l * DMODEL * DMODEL, fc_b + (size_t)l * DMODEL,
                gamma, beta, Xc, Xbc);
        }
    }

    zero_kernel<<<BATCH * DMODEL / 256, 256, 0, stream>>>(pooled);
    pool_kernel<<<dim3(BATCH, 16), 128, 0, stream>>>(X, pooled);
    fc1_kernel<<<dim3(FFDIM / 256, BATCH), 256, 0, stream>>>(pooled, fc1_w, fc1_b, hbuf);
    fc2_kernel<<<BATCH, 256, 0, stream>>>(hbuf, fc2_w, fc2_b, out);
}

// Round 5
// 1028.114 us; speedup vs baseline: 9.4730x; 1.3013x over previous
//
#include <hip/hip_runtime.h>
#include <cmath>

#define BS_TOK 32768      // B*S
#define DMODEL 512
#define NHEAD 8
#define DHEAD 64
#define NLAYER 3
#define FFDIM 2048
#define NCLS 6
#define BATCH 32
#define SEQ 1024
#define QKVW 1536         // 3*D

typedef short short8 __attribute__((ext_vector_type(8)));
typedef float float4v __attribute__((ext_vector_type(4)));
#define MFMA_BF16 __builtin_amdgcn_mfma_f32_16x16x32_bf16
#define QSCALE 0.18033688011112042f   // 0.125 * log2(e)

__device__ __forceinline__ unsigned short f2bf(float x) {
    return (unsigned short)((__float_as_uint(x) + 0x8000u) >> 16);  // round-half-away
}

// ---------------- embedding + sinusoidal PE -> X fp32 + Xb bf16 ----------------
__global__ __launch_bounds__(128) void embed_pe_kernel(const int* __restrict__ tokens,
                                                       const float* __restrict__ emb,
                                                       float* __restrict__ X,
                                                       unsigned short* __restrict__ Xb) {
    int t = blockIdx.x;
    int pos = t & (SEQ - 1);
    int tok = tokens[t];
    int d0 = threadIdx.x * 4;
    float4 e = *(const float4*)(emb + (size_t)tok * DMODEL + d0);
    const float c = -9.210340371976184f / 512.0f;
    float div0 = expf((float)d0 * c);
    float div1 = expf((float)(d0 + 2) * c);
    float a0 = (float)pos * div0;
    float a1 = (float)pos * div1;
    e.x += sinf(a0); e.y += cosf(a0);
    e.z += sinf(a1); e.w += cosf(a1);
    *(float4*)(X + (size_t)t * DMODEL + d0) = e;
    *(ushort4*)(Xb + (size_t)t * DMODEL + d0) =
        make_ushort4(f2bf(e.x), f2bf(e.y), f2bf(e.z), f2bf(e.w));
}

// ---------------- generic transpose+convert (fc_w): f32 [R][C] -> bf16 [C][R] ----------------
__global__ __launch_bounds__(256) void transcvt_kernel(const float* __restrict__ in,
                                                       unsigned short* __restrict__ out,
                                                       int R, int C) {
    __shared__ float t[32][33];
    size_t base = (size_t)blockIdx.z * R * C;
    int c0 = blockIdx.x * 32, r0 = blockIdx.y * 32;
    int tx = threadIdx.x & 31, ty = threadIdx.x >> 5;
#pragma unroll
    for (int i = 0; i < 4; i++)
        t[ty + i * 8][tx] = in[base + (size_t)(r0 + ty + i * 8) * C + c0 + tx];
    __syncthreads();
#pragma unroll
    for (int i = 0; i < 4; i++)
        out[base + (size_t)(c0 + ty + i * 8) * R + r0 + tx] = f2bf(t[tx][ty + i * 8]);
}

// ---------------- qkv_w transpose+convert with head-permute + Q prescale ----------------
// out[l][n][k]: n<512 -> Q (head h=n>>6, scaled), n<1024 -> K, else V.
__global__ __launch_bounds__(256) void transcvt_qkv_kernel(const float* __restrict__ in,
                                                           unsigned short* __restrict__ out) {
    __shared__ float t[32][33];
    int l = blockIdx.z;
    int n0 = blockIdx.x * 32, r0 = blockIdx.y * 32;
    int seg = n0 >> 9, nn = n0 & 511, h = nn >> 6, d0 = nn & 63;
    int c0 = h * 192 + seg * 64 + d0;
    float s = (seg == 0) ? QSCALE : 1.f;
    const float* inp = in + (size_t)l * DMODEL * QKVW;
    unsigned short* op = out + (size_t)l * QKVW * DMODEL;
    int tx = threadIdx.x & 31, ty = threadIdx.x >> 5;
#pragma unroll
    for (int i = 0; i < 4; i++)
        t[ty + i * 8][tx] = inp[(size_t)(r0 + ty + i * 8) * QKVW + c0 + tx];
    __syncthreads();
#pragma unroll
    for (int i = 0; i < 4; i++)
        op[(size_t)(n0 + ty + i * 8) * DMODEL + r0 + tx] = f2bf(t[tx][ty + i * 8] * s);
}

// ---------------- permuted (+scaled) qkv bias ----------------
__global__ __launch_bounds__(256) void permbias_kernel(const float* __restrict__ qkv_b,
                                                       float* __restrict__ pb) {
    int i = blockIdx.x * 256 + threadIdx.x;   // < L*1536
    int l = i / QKVW, n = i - l * QKVW;
    int seg = n >> 9, nn = n & 511, h = nn >> 6, d = nn & 63;
    float s = (seg == 0) ? QSCALE : 1.f;
    pb[i] = qkv_b[l * QKVW + h * 192 + seg * 64 + d] * s;
}

// ---------------- QKV GEMM: [M,1536]perm = Xb[M,512] @ Wt^T + pb ----------------
// bn<1024 -> QKc [tok][1024]; bn>=1024 -> V^T to Vt[bh][d][s] (b64-packed rows).
__global__ __launch_bounds__(256) void gemm_qkv_kernel(const unsigned short* __restrict__ A,
                                                       const unsigned short* __restrict__ Bt,
                                                       const float* __restrict__ pb,
                                                       unsigned short* __restrict__ QKc,
                                                       unsigned short* __restrict__ Vt,
                                                       int M) {
    __shared__ unsigned short As[128 * 40];
    __shared__ unsigned short Bs[128 * 40];
    int bm = blockIdx.y * 128, bn = blockIdx.x * 128;
    int tid = threadIdx.x;
    int w = tid >> 6, lane = tid & 63, l15 = lane & 15, quad = lane >> 4;
    int wm = (w & 1) * 64, wn = (w >> 1) * 64;

    float4v acc[4][4];
    float4v z = {0.f, 0.f, 0.f, 0.f};
#pragma unroll
    for (int i = 0; i < 4; i++)
#pragma unroll
        for (int j = 0; j < 4; j++) acc[i][j] = z;

    int r0 = tid >> 2, o0 = (tid & 3) * 8;
    int r1 = (tid + 256) >> 2, o1 = (tid & 3) * 8;

    for (int k0 = 0; k0 < DMODEL; k0 += 32) {
        __syncthreads();
        *(short8*)&As[r0 * 40 + o0] = *(const short8*)(A + (size_t)(bm + r0) * DMODEL + k0 + o0);
        *(short8*)&As[r1 * 40 + o1] = *(const short8*)(A + (size_t)(bm + r1) * DMODEL + k0 + o1);
        *(short8*)&Bs[r0 * 40 + o0] = *(const short8*)(Bt + (size_t)(bn + r0) * DMODEL + k0 + o0);
        *(short8*)&Bs[r1 * 40 + o1] = *(const short8*)(Bt + (size_t)(bn + r1) * DMODEL + k0 + o1);
        __syncthreads();
        short8 af[4], bf[4];
#pragma unroll
        for (int i = 0; i < 4; i++)
            af[i] = *(short8*)&As[(wm + i * 16 + l15) * 40 + quad * 8];
#pragma unroll
        for (int j = 0; j < 4; j++)
            bf[j] = *(short8*)&Bs[(wn + j * 16 + l15) * 40 + quad * 8];
#pragma unroll
        for (int i = 0; i < 4; i++)
#pragma unroll
            for (int j = 0; j < 4; j++)
                acc[i][j] = MFMA_BF16(af[i], bf[j], acc[i][j], 0, 0, 0);
    }

    float bj[4];
#pragma unroll
    for (int j = 0; j < 4; j++) bj[j] = pb[bn + wn + j * 16 + l15];

    if (bn < 1024) {          // Q | K -> row-major QKc[tok][1024]
#pragma unroll
        for (int i = 0; i < 4; i++)
#pragma unroll
            for (int r = 0; r < 4; r++) {
                size_t row = (size_t)(bm + wm + i * 16 + quad * 4 + r);
#pragma unroll
                for (int j = 0; j < 4; j++)
                    QKc[row * 1024 + bn + wn + j * 16 + l15] = f2bf(acc[i][j][r] + bj[j]);
            }
    } else {                  // V -> transposed Vt[bh][d][s]
        int bl = bm >> 10;
        int sbase = (bm & 1023) + wm;
#pragma unroll
        for (int j = 0; j < 4; j++) {
            int colp = bn - 1024 + wn + j * 16 + l15;
            int h = colp >> 6, d = colp & 63;
            unsigned short* vb = Vt + ((size_t)(bl * 8 + h) * 64 + d) * 1024 + sbase;
#pragma unroll
            for (int i = 0; i < 4; i++) {
                ushort4 v4 = make_ushort4(f2bf(acc[i][j][0] + bj[j]),
                                          f2bf(acc[i][j][1] + bj[j]),
                                          f2bf(acc[i][j][2] + bj[j]),
                                          f2bf(acc[i][j][3] + bj[j]));
                *(ushort4*)(vb + i * 16 + quad * 4) = v4;
            }
        }
    }
}

// ---------------- bf16 MFMA flash attention, max-free softmax ----------------
// QKc [tok][Q512|K512] (Q pre-scaled by 0.125*log2e), Vt [bh][64][1024]. O bf16 [tok][512].
__global__ __launch_bounds__(256) void attn_kernel(const unsigned short* __restrict__ QKc,
                                                   const unsigned short* __restrict__ Vt,
                                                   unsigned short* __restrict__ O) {
    __shared__ unsigned short Ks[64 * 72];    // K[kcol][d]
    __shared__ unsigned short Vts[64 * 72];   // V^T[d][k]
    __shared__ unsigned short Ps[4 * 32 * 72];
    int bh = blockIdx.y;
    int b = bh >> 3, h = bh & 7;
    int q0 = blockIdx.x * 128;
    int tid = threadIdx.x;
    int w = tid >> 6, lane = tid & 63, l15 = lane & 15, quad = lane >> 4;
    unsigned short* Psb = &Ps[w * 32 * 72];
    const unsigned short* Kg = QKc + (size_t)b * SEQ * 1024 + 512 + h * 64;
    const unsigned short* Vg = Vt + (size_t)bh * 64 * 1024;

    short8 qf[2][2];
#pragma unroll
    for (int i = 0; i < 2; i++) {
        const unsigned short* qb =
            QKc + (size_t)(b * SEQ + q0 + w * 32 + i * 16 + l15) * 1024 + h * 64;
        qf[i][0] = *(const short8*)(qb + quad * 8);
        qf[i][1] = *(const short8*)(qb + 32 + quad * 8);
    }

    float lsum[2][4] = {{0.f, 0.f, 0.f, 0.f}, {0.f, 0.f, 0.f, 0.f}};
    float4v accO[2][4];
    float4v z = {0.f, 0.f, 0.f, 0.f};
#pragma unroll
    for (int i = 0; i < 2; i++)
#pragma unroll
        for (int dc = 0; dc < 4; dc++) accO[i][dc] = z;

    int sr = tid >> 2, so = (tid & 3) * 16;   // staging: row, 16-col chunk

    for (int jt = 0; jt < SEQ / 64; jt++) {
        __syncthreads();
        {
            const unsigned short* kg = Kg + (size_t)(jt * 64 + sr) * 1024 + so;
            *(short8*)&Ks[sr * 72 + so] = *(const short8*)kg;
            *(short8*)&Ks[sr * 72 + so + 8] = *(const short8*)(kg + 8);
            const unsigned short* vg = Vg + (size_t)sr * 1024 + jt * 64 + so;
            *(short8*)&Vts[sr * 72 + so] = *(const short8*)vg;
            *(short8*)&Vts[sr * 72 + so + 8] = *(const short8*)(vg + 8);
        }
        __syncthreads();

        // S: 32 q-rows x 64 k-cols per wave
        float4v sv[2][4];
#pragma unroll
        for (int jc = 0; jc < 4; jc++) {
            short8 kf0 = *(short8*)&Ks[(jc * 16 + l15) * 72 + quad * 8];
            short8 kf1 = *(short8*)&Ks[(jc * 16 + l15) * 72 + 32 + quad * 8];
#pragma unroll
            for (int i = 0; i < 2; i++) {
                float4v s = MFMA_BF16(qf[i][0], kf0, z, 0, 0, 0);
                sv[i][jc] = MFMA_BF16(qf[i][1], kf1, s, 0, 0, 0);
            }
        }

        // max-free softmax: P = 2^s, per-lane partial row sums (no shuffles in loop)
#pragma unroll
        for (int i = 0; i < 2; i++)
#pragma unroll
            for (int jc = 0; jc < 4; jc++)
#pragma unroll
                for (int r = 0; r < 4; r++) {
                    float p = exp2f(sv[i][jc][r]);
                    lsum[i][r] += p;
                    Psb[(i * 16 + quad * 4 + r) * 72 + jc * 16 + l15] = f2bf(p);
                }

        // P frags (wave-private LDS; in-order DS within wave => no barrier)
        short8 pf[2][2];
#pragma unroll
        for (int i = 0; i < 2; i++) {
            pf[i][0] = *(short8*)&Psb[(i * 16 + l15) * 72 + quad * 8];
            pf[i][1] = *(short8*)&Psb[(i * 16 + l15) * 72 + 32 + quad * 8];
        }

        // PV
#pragma unroll
        for (int dc = 0; dc < 4; dc++) {
            short8 vf0 = *(short8*)&Vts[(dc * 16 + l15) * 72 + quad * 8];
            short8 vf1 = *(short8*)&Vts[(dc * 16 + l15) * 72 + 32 + quad * 8];
#pragma unroll
            for (int i = 0; i < 2; i++) {
                accO[i][dc] = MFMA_BF16(pf[i][0], vf0, accO[i][dc], 0, 0, 0);
                accO[i][dc] = MFMA_BF16(pf[i][1], vf1, accO[i][dc], 0, 0, 0);
            }
        }
    }

    // epilogue: reduce row sums across 16 lanes, normalize, store
#pragma unroll
    for (int i = 0; i < 2; i++)
#pragma unroll
        for (int r = 0; r < 4; r++) {
            float s = lsum[i][r];
#pragma unroll
            for (int mask = 1; mask < 16; mask <<= 1) s += __shfl_xor(s, mask);
            float rinv = 1.f / s;
            size_t row = (size_t)(b * SEQ + q0 + w * 32 + i * 16 + quad * 4 + r);
#pragma unroll
            for (int dc = 0; dc < 4; dc++)
                O[row * DMODEL + h * DHEAD + dc * 16 + l15] = f2bf(accO[i][dc][r] * rinv);
        }
}

// ---------------- fused out-proj + bias + residual + LayerNorm ----------------
__global__ __launch_bounds__(256) void proj_ln_kernel(const unsigned short* __restrict__ A,
                                                      const unsigned short* __restrict__ Bt,
                                                      const float* __restrict__ bias,
                                                      const float* __restrict__ gamma,
                                                      const float* __restrict__ beta,
                                                      float* __restrict__ X,
                                                      unsigned short* __restrict__ Xb) {
    __shared__ unsigned short As[32 * 40];
    __shared__ unsigned short Bs[512 * 40];
    __shared__ float redS[4][32], redQ[4][32];
    int bm = blockIdx.x * 32;
    int tid = threadIdx.x;
    int w = tid >> 6, lane = tid & 63, l15 = lane & 15, quad = lane >> 4;
    int wn = w * 128;

    float4v acc[2][8];
    float4v z = {0.f, 0.f, 0.f, 0.f};
#pragma unroll
    for (int i = 0; i < 2; i++)
#pragma unroll
        for (int j = 0; j < 8; j++) acc[i][j] = z;

    for (int k0 = 0; k0 < DMODEL; k0 += 32) {
        __syncthreads();
        if (tid < 128) {
            int r = tid >> 2, o = (tid & 3) * 8;
            *(short8*)&As[r * 40 + o] = *(const short8*)(A + (size_t)(bm + r) * DMODEL + k0 + o);
        }
#pragma unroll
        for (int u = 0; u < 8; u++) {
            int c = tid + u * 256;
            int r = c >> 2, o = (c & 3) * 8;
            *(short8*)&Bs[r * 40 + o] = *(const short8*)(Bt + (size_t)r * DMODEL + k0 + o);
        }
        __syncthreads();
        short8 af[2];
#pragma unroll
        for (int i = 0; i < 2; i++)
            af[i] = *(short8*)&As[(i * 16 + l15) * 40 + quad * 8];
#pragma unroll
        for (int j = 0; j < 8; j++) {
            short8 bf = *(short8*)&Bs[(wn + j * 16 + l15) * 40 + quad * 8];
            acc[0][j] = MFMA_BF16(af[0], bf, acc[0][j], 0, 0, 0);
            acc[1][j] = MFMA_BF16(af[1], bf, acc[1][j], 0, 0, 0);
        }
    }

    float bj[8], g[8], be[8];
#pragma unroll
    for (int j = 0; j < 8; j++) {
        int col = wn + j * 16 + l15;
        bj[j] = bias[col]; g[j] = gamma[col]; be[j] = beta[col];
    }

    float o[2][4][8];
#pragma unroll
    for (int i = 0; i < 2; i++)
#pragma unroll
        for (int r = 0; r < 4; r++) {
            int lrow = i * 16 + quad * 4 + r;
            size_t row = (size_t)(bm + lrow);
            float ss = 0.f, qq = 0.f;
#pragma unroll
            for (int j = 0; j < 8; j++) {
                float v = acc[i][j][r] + bj[j] + X[row * DMODEL + wn + j * 16 + l15];
                o[i][r][j] = v; ss += v; qq += v * v;
            }
#pragma unroll
            for (int mask = 1; mask < 16; mask <<= 1) {
                ss += __shfl_xor(ss, mask);
                qq += __shfl_xor(qq, mask);
            }
            if (l15 == 0) { redS[w][lrow] = ss; redQ[w][lrow] = qq; }
        }
    __syncthreads();
#pragma unroll
    for (int i = 0; i < 2; i++)
#pragma unroll
        for (int r = 0; r < 4; r++) {
            int lrow = i * 16 + quad * 4 + r;
            float S = redS[0][lrow] + redS[1][lrow] + redS[2][lrow] + redS[3][lrow];
            float Q = redQ[0][lrow] + redQ[1][lrow] + redQ[2][lrow] + redQ[3][lrow];
            float mean = S * (1.f / 512.f);
            float var = Q * (1.f / 512.f) - mean * mean;
            float rstd = rsqrtf(var + 1e-5f);
            size_t row = (size_t)(bm + lrow);
#pragma unroll
            for (int j = 0; j < 8; j++) {
                float n = (o[i][r][j] - mean) * rstd * g[j] + be[j];
                X[row * DMODEL + wn + j * 16 + l15] = n;
                Xb[row * DMODEL + wn + j * 16 + l15] = f2bf(n);
            }
        }
}

// ---------------- pooled zero + two-stage mean pool ----------------
__global__ __launch_bounds__(256) void zero_kernel(float* __restrict__ p) {
    p[blockIdx.x * 256 + threadIdx.x] = 0.f;
}
__global__ __launch_bounds__(128) void pool_kernel(const float* __restrict__ X,
                                                   float* __restrict__ pooled) {
    int b = blockIdx.x, ch = blockIdx.y;
    int d0 = threadIdx.x * 4;
    float4 acc = make_float4(0.f, 0.f, 0.f, 0.f);
    const float* base = X + (size_t)(b * SEQ + ch * 64) * DMODEL + d0;
    for (int s2 = 0; s2 < 64; s2++) {
        float4 v = *(const float4*)(base + (size_t)s2 * DMODEL);
        acc.x += v.x; acc.y += v.y; acc.z += v.z; acc.w += v.w;
    }
    atomicAdd(pooled + b * DMODEL + d0 + 0, acc.x);
    atomicAdd(pooled + b * DMODEL + d0 + 1, acc.y);
    atomicAdd(pooled + b * DMODEL + d0 + 2, acc.z);
    atomicAdd(pooled + b * DMODEL + d0 + 3, acc.w);
}

// ---------------- MLP head ----------------
__global__ __launch_bounds__(256) void fc1_kernel(const float* __restrict__ pooled,
                                                  const float* __restrict__ fc1_w,
                                                  const float* __restrict__ fc1_b,
                                                  float* __restrict__ h) {
    __shared__ float p[DMODEL];
    int ffc = blockIdx.x, b = blockIdx.y;
    int tid = threadIdx.x;
    p[tid] = pooled[b * DMODEL + tid] * (1.f / 1024.f);
    p[tid + 256] = pooled[b * DMODEL + tid + 256] * (1.f / 1024.f);
    __syncthreads();
    int ff = ffc * 256 + tid;
    float acc = fc1_b[ff];
    for (int k = 0; k < DMODEL; k++) acc += p[k] * fc1_w[(size_t)k * FFDIM + ff];
    h[(size_t)b * FFDIM + ff] = fmaxf(acc, 0.f);
}

__global__ __launch_bounds__(256) void fc2_kernel(const float* __restrict__ h,
                                                  const float* __restrict__ fc2_w,
                                                  const float* __restrict__ fc2_b,
                                                  float* __restrict__ out) {
    __shared__ float red[NCLS][256];
    int b = blockIdx.x, tid = threadIdx.x;
    float a[NCLS];
#pragma unroll
    for (int c = 0; c < NCLS; c++) a[c] = 0.f;
    int k0 = tid * 8;
#pragma unroll
    for (int u = 0; u < 8; u++) {
        float hv = h[(size_t)b * FFDIM + k0 + u];
#pragma unroll
        for (int c = 0; c < NCLS; c++) a[c] += hv * fc2_w[(k0 + u) * NCLS + c];
    }
#pragma unroll
    for (int c = 0; c < NCLS; c++) red[c][tid] = a[c];
    __syncthreads();
    if (tid < NCLS) {
        float s = 0.f;
        for (int i = 0; i < 256; i++) s += red[tid][i];
        out[b * NCLS + tid] = s + fc2_b[tid];
    }
}

extern "C" void kernel_launch(void* const* d_in, const int* in_sizes, int n_in,
                              void* d_out, int out_size, void* d_ws, size_t ws_size,
                              hipStream_t stream) {
    const int* tokens = (const int*)d_in[0];
    const float* emb = (const float*)d_in[1];
    const float* qkv_w = (const float*)d_in[2];
    const float* qkv_b = (const float*)d_in[3];
    const float* fc_w = (const float*)d_in[4];
    const float* fc_b = (const float*)d_in[5];
    const float* gamma = (const float*)d_in[6];
    const float* beta = (const float*)d_in[7];
    const float* fc1_w = (const float*)d_in[8];
    const float* fc1_b = (const float*)d_in[9];
    const float* fc2_w = (const float*)d_in[10];
    const float* fc2_b = (const float*)d_in[11];
    float* out = (float*)d_out;

    char* p = (char*)d_ws;
    float* X = (float*)p;                         p += (size_t)BS_TOK * DMODEL * 4;  // 64 MB
    unsigned short* Xb = (unsigned short*)p;      p += (size_t)BS_TOK * DMODEL * 2;  // 32 MB
    float* pooled = (float*)p;                    p += (size_t)BATCH * DMODEL * 4;
    float* hbuf = (float*)p;                      p += (size_t)BATCH * FFDIM * 4;
    float* pb = (float*)p;                        p += (size_t)NLAYER * QKVW * 4;
    unsigned short* qkv_wbt = (unsigned short*)p; p += (size_t)NLAYER * QKVW * DMODEL * 2;
    unsigned short* fc_wt = (unsigned short*)p;   p += (size_t)NLAYER * DMODEL * DMODEL * 2;
    size_t fixed_bytes = (size_t)(p - (char*)d_ws);
    // per batch: QKc 2MB + Vt 1MB + Oc 1MB
    size_t per_batch = (size_t)SEQ * 1024 * 2 + (size_t)NHEAD * 64 * SEQ * 2
                     + (size_t)SEQ * DMODEL * 2;
    int chunkB = 1;
    for (int cb = 32; cb >= 1; cb >>= 1)
        if (fixed_bytes + (size_t)cb * per_batch <= ws_size) { chunkB = cb; break; }
    unsigned short* QKc = (unsigned short*)p;     p += (size_t)chunkB * SEQ * 1024 * 2;
    unsigned short* Vt = (unsigned short*)p;      p += (size_t)chunkB * NHEAD * 64 * SEQ * 2;
    unsigned short* Oc = (unsigned short*)p;
    int rows = chunkB * SEQ;
    int nchunks = BATCH / chunkB;

    embed_pe_kernel<<<BS_TOK, 128, 0, stream>>>(tokens, emb, X, Xb);
    permbias_kernel<<<NLAYER * QKVW / 256, 256, 0, stream>>>(qkv_b, pb);
    transcvt_qkv_kernel<<<dim3(QKVW / 32, DMODEL / 32, NLAYER), 256, 0, stream>>>(
        qkv_w, qkv_wbt);
    transcvt_kernel<<<dim3(DMODEL / 32, DMODEL / 32, NLAYER), 256, 0, stream>>>(
        fc_w, fc_wt, DMODEL, DMODEL);

    for (int l = 0; l < NLAYER; l++) {
        for (int c = 0; c < nchunks; c++) {
            unsigned short* Xbc = Xb + (size_t)c * rows * DMODEL;
            float* Xc = X + (size_t)c * rows * DMODEL;
            gemm_qkv_kernel<<<dim3(QKVW / 128, rows / 128), 256, 0, stream>>>(
                Xbc, qkv_wbt + (size_t)l * QKVW * DMODEL, pb + (size_t)l * QKVW,
                QKc, Vt, rows);
            attn_kernel<<<dim3(SEQ / 128, chunkB * NHEAD), 256, 0, stream>>>(QKc, Vt, Oc);
            proj_ln_kernel<<<rows / 32, 256, 0, stream>>>(
                Oc, fc_wt + (size_t)l * DMODEL * DMODEL, fc_b + (size_t)l * DMODEL,
                gamma, beta, Xc, Xbc);
        }
    }

    zero_kernel<<<BATCH * DMODEL / 256, 256, 0, stream>>>(pooled);
    pool_kernel<<<dim3(BATCH, 16), 128, 0, stream>>>(X, pooled);
    fc1_kernel<<<dim3(FFDIM / 256, BATCH), 256, 0, stream>>>(pooled, fc1_w, fc1_b, hbuf);
    fc2_kernel<<<BATCH, 256, 0, stream>>>(hbuf, fc2_w, fc2_b, out);
}